// Round 4
// baseline (138.053 us; speedup 1.0000x reference)
//
#include <hip/hip_runtime.h>

#define NPTS 131072
#define G0 512
#define G1 512
#define G2 128

#define SKIN_BLOCKS  512
#define TRANS_BLOCKS 576
#define FEAT_BLOCKS  48

#define OFF1 (4*G0*32)
#define OFF2 (4*(G0+G1)*32)
#define LTOT (4*(G0+G1+G2)*32)

typedef float v4f __attribute__((ext_vector_type(4)));
typedef __attribute__((ext_vector_type(8))) short short8;

// persistent device scratch (fully rewritten every launch)
__device__ unsigned short g_lines16[LTOT + 32];   // bf16 [axis][pose][g][r], 64-B rows, +pad
__device__ unsigned short g_featB[3*4*2*64*8];    // bf16 [plane][s][tcol][lane][j] MFMA-B order
__device__ float4 g_pos[NPTS];                    // raw grid positions per axis

__device__ __forceinline__ unsigned short bf16rne(float x){
  unsigned int u = __float_as_uint(x);
  u += 0x7fffu + ((u >> 16) & 1u);
  return (unsigned short)(u >> 16);
}

__device__ __forceinline__ void cvt8(uint4 r, float* f){
  f[0] = __uint_as_float(r.x << 16); f[1] = __uint_as_float(r.x & 0xffff0000u);
  f[2] = __uint_as_float(r.y << 16); f[3] = __uint_as_float(r.y & 0xffff0000u);
  f[4] = __uint_as_float(r.z << 16); f[5] = __uint_as_float(r.z & 0xffff0000u);
  f[6] = __uint_as_float(r.w << 16); f[7] = __uint_as_float(r.w & 0xffff0000u);
}

__device__ __forceinline__ void lerp_regs(uint4 r0, uint4 r1, float w, float* c){
  float a[8], b[8];
  cvt8(r0, a); cvt8(r1, b);
  #pragma unroll
  for (int j = 0; j < 8; j++) c[j] = fmaf(w, b[j] - a[j], a[j]);
}

// pack two fp32 -> bf16x2 (lo in low half) via +0x8000 round, one v_perm
__device__ __forceinline__ unsigned int pack2(float lo, float hi){
  unsigned int ul = __float_as_uint(lo) + 0x8000u;
  unsigned int uh = __float_as_uint(hi) + 0x8000u;
  return __builtin_amdgcn_perm(uh, ul, 0x07060302u);
}

// ---------------- kernel 1: skin + bf16 line transpose + featB prep ----------------
__global__ __launch_bounds__(256) void prep_skin(
    const float* __restrict__ pts, const float* __restrict__ dirs,
    const float* __restrict__ sw,  const float* __restrict__ Am,
    const float* __restrict__ Bm,  const float* __restrict__ tb,
    const float* __restrict__ c0,  const float* __restrict__ c1,
    const float* __restrict__ c2,  const float* __restrict__ f0,
    const float* __restrict__ f1,  const float* __restrict__ f2,
    const float* __restrict__ tw,  const int* __restrict__ topk_id,
    float* __restrict__ out)
{
  const int bid = blockIdx.x;
  const int tid = threadIdx.x;

  if (bid >= SKIN_BLOCKS) {
    int pb = bid - SKIN_BLOCKS;
    if (pb < TRANS_BLOCKS) {
      int e = pb*256 + tid;
      const float* src; int logG, outoff;
      if (e < 65536)       { src = c0; logG = 9; outoff = 0; }
      else if (e < 131072) { e -= 65536;  src = c1; logG = 9; outoff = OFF1; }
      else                 { e -= 131072; src = c2; logG = 7; outoff = OFF2; }
      const int G = 1 << logG;
      int g  = e & (G-1);
      int t  = e >> logG;
      int r  = t & 31;
      int kk = t >> 5;
      int id = topk_id[kk];
      float v = src[(id*32 + r)*G + g];
      g_lines16[outoff + (kk*G + g)*32 + r] = bf16rne(v);
    } else {
      int e = (pb - TRANS_BLOCKS)*256 + tid;
      if (e < 3*4*2*64*8) {
        int j    =  e        & 7;
        int lane = (e >> 3)  & 63;
        int tcol = (e >> 9)  & 1;
        int s    = (e >> 10) & 3;
        int p    =  e >> 12;
        int r = ((lane >> 4) << 3) + j;
        int cc = tcol*16 + (lane & 15);
        const float* f = (p == 0) ? f0 : ((p == 1) ? f1 : f2);
        float v = tw[s] * f[(topk_id[s]*32 + r)*32 + cc];
        g_featB[e] = bf16rne(v);
      }
    }
    return;
  }

  // -------- skin path --------
  if (bid == 0 && tid < 32) g_lines16[LTOT + tid] = 0;  // finite pad

  __shared__ float sA[384];
  __shared__ float sB[384];
  for (int i = tid; i < 384; i += 256){ sA[i] = Am[i]; sB[i] = Bm[i]; }
  __syncthreads();

  const int n = bid*256 + tid;
  float swv[24];
  {
    const float4* swp = reinterpret_cast<const float4*>(sw + n*24);
    #pragma unroll
    for (int i = 0; i < 6; i++){
      float4 v = swp[i];
      swv[4*i] = v.x; swv[4*i+1] = v.y; swv[4*i+2] = v.z; swv[4*i+3] = v.w;
    }
  }
  float RA[9] = {0,0,0,0,0,0,0,0,0}, tA[3] = {0,0,0};
  float RB[9] = {0,0,0,0,0,0,0,0,0}, tB[3] = {0,0,0};
  #pragma unroll
  for (int j = 0; j < 24; j++){
    float w = swv[j];
    const float* a = sA + j*16;
    const float* b = sB + j*16;
    RA[0] = fmaf(w, a[0], RA[0]); RA[1] = fmaf(w, a[1], RA[1]); RA[2] = fmaf(w, a[2], RA[2]); tA[0] = fmaf(w, a[3],  tA[0]);
    RA[3] = fmaf(w, a[4], RA[3]); RA[4] = fmaf(w, a[5], RA[4]); RA[5] = fmaf(w, a[6], RA[5]); tA[1] = fmaf(w, a[7],  tA[1]);
    RA[6] = fmaf(w, a[8], RA[6]); RA[7] = fmaf(w, a[9], RA[7]); RA[8] = fmaf(w, a[10],RA[8]); tA[2] = fmaf(w, a[11], tA[2]);
    RB[0] = fmaf(w, b[0], RB[0]); RB[1] = fmaf(w, b[1], RB[1]); RB[2] = fmaf(w, b[2], RB[2]); tB[0] = fmaf(w, b[3],  tB[0]);
    RB[3] = fmaf(w, b[4], RB[3]); RB[4] = fmaf(w, b[5], RB[4]); RB[5] = fmaf(w, b[6], RB[5]); tB[1] = fmaf(w, b[7],  tB[1]);
    RB[6] = fmaf(w, b[8], RB[6]); RB[7] = fmaf(w, b[9], RB[7]); RB[8] = fmaf(w, b[10],RB[8]); tB[2] = fmaf(w, b[11], tB[2]);
  }
  float c00 = RA[4]*RA[8] - RA[5]*RA[7];
  float c01 = RA[5]*RA[6] - RA[3]*RA[8];
  float c02 = RA[3]*RA[7] - RA[4]*RA[6];
  float det = RA[0]*c00 + RA[1]*c01 + RA[2]*c02;
  float idet = 1.0f/det;
  float i00 = c00*idet;
  float i01 = (RA[2]*RA[7] - RA[1]*RA[8])*idet;
  float i02 = (RA[1]*RA[5] - RA[2]*RA[4])*idet;
  float i10 = c01*idet;
  float i11 = (RA[0]*RA[8] - RA[2]*RA[6])*idet;
  float i12 = (RA[2]*RA[3] - RA[0]*RA[5])*idet;
  float i20 = c02*idet;
  float i21 = (RA[1]*RA[6] - RA[0]*RA[7])*idet;
  float i22 = (RA[0]*RA[4] - RA[1]*RA[3])*idet;

  float px = pts[n*3+0], py = pts[n*3+1], pz = pts[n*3+2];
  float dx = dirs[n*3+0], dy = dirs[n*3+1], dz = dirs[n*3+2];
  float qx = px - tA[0], qy = py - tA[1], qz = pz - tA[2];
  float tpx = i00*qx + i01*qy + i02*qz;
  float tpy = i10*qx + i11*qy + i12*qz;
  float tpz = i20*qx + i21*qy + i22*qz;
  float cx = RB[0]*tpx + RB[1]*tpy + RB[2]*tpz + tB[0];
  float cy = RB[3]*tpx + RB[4]*tpy + RB[5]*tpz + tB[1];
  float cz = RB[6]*tpx + RB[7]*tpy + RB[8]*tpz + tB[2];
  float tdx = i00*dx + i01*dy + i02*dz;
  float tdy = i10*dx + i11*dy + i12*dz;
  float tdz = i20*dx + i21*dy + i22*dz;
  float cdx = RB[0]*tdx + RB[1]*tdy + RB[2]*tdz;
  float cdy = RB[3]*tdx + RB[4]*tdy + RB[5]*tdz;
  float cdz = RB[6]*tdx + RB[7]*tdy + RB[8]*tdz;

  {
    float* o = out + (size_t)n*102;
    o[0] = cx; o[1] = cy; o[2] = cz; o[3] = cdx; o[4] = cdy; o[5] = cdz;
  }
  {
    float lo0 = tb[0], lo1 = tb[1], lo2 = tb[2];
    float hi0 = tb[3], hi1 = tb[4], hi2 = tb[5];
    float x0 = (cx - lo0)/(hi0 - lo0)*2.0f - 1.0f;
    float x1 = (cy - lo1)/(hi1 - lo1)*2.0f - 1.0f;
    float x2 = (cz - lo2)/(hi2 - lo2)*2.0f - 1.0f;
    float4 p;
    p.x = (x0 + 1.0f)*0.5f*(float)(G0-1);
    p.y = (x1 + 1.0f)*0.5f*(float)(G1-1);
    p.z = (x2 + 1.0f)*0.5f*(float)(G2-1);
    p.w = 0.0f;
    g_pos[n] = p;
  }
}

// ---------------- kernel 2: einsum via MFMA, full register prefetch of gathers ----------------
__global__ __launch_bounds__(256) void einsum_mfma(float* __restrict__ out)
{
  const int tid  = threadIdx.x;
  const int lane = tid & 63;
  const int wv   = tid >> 6;
  const int m    = lane & 15;
  const int q    = lane >> 4;
  const int tile = blockIdx.x*4 + wv;
  const int pl   = tile*16 + m;

  float4 pos = g_pos[pl];
  float pc0 = fminf(fmaxf(pos.x, 0.0f), (float)(G0-1));
  float pc1 = fminf(fmaxf(pos.y, 0.0f), (float)(G1-1));
  float pc2 = fminf(fmaxf(pos.z, 0.0f), (float)(G2-1));
  float fl0 = floorf(pc0), fl1 = floorf(pc1), fl2 = floorf(pc2);
  int a0 = (int)fl0, a1 = (int)fl1, a2 = (int)fl2;
  float w0 = pc0 - fl0, w1 = pc1 - fl1, w2 = pc2 - fl2;

  const unsigned short* lt0 = g_lines16;
  const unsigned short* lt1 = g_lines16 + OFF1;
  const unsigned short* lt2 = g_lines16 + OFF2;
  const short8* fb = reinterpret_cast<const short8*>(g_featB);

  // ---- prefetch ALL 24 row loads (12 pairs) into registers: 24-deep MLP ----
  uint4 R0[12], R1[12];   // [axis*4 + s], row i0 and row i0+1
  #pragma unroll
  for (int s = 0; s < 4; s++){
    const unsigned short* p = lt0 + (s*G0 + a0)*32 + q*8;
    R0[s]   = *(const uint4*)p;
    R1[s]   = *(const uint4*)(p + 32);
  }
  #pragma unroll
  for (int s = 0; s < 4; s++){
    const unsigned short* p = lt1 + (s*G1 + a1)*32 + q*8;
    R0[4+s] = *(const uint4*)p;
    R1[4+s] = *(const uint4*)(p + 32);
  }
  #pragma unroll
  for (int s = 0; s < 4; s++){
    const unsigned short* p = lt2 + (s*G2 + a2)*32 + q*8;
    R0[8+s] = *(const uint4*)p;
    R1[8+s] = *(const uint4*)(p + 32);
  }

  v4f acc00 = {0,0,0,0}, acc01 = {0,0,0,0};
  v4f acc10 = {0,0,0,0}, acc11 = {0,0,0,0};
  v4f acc20 = {0,0,0,0}, acc21 = {0,0,0,0};

  #pragma unroll
  for (int s = 0; s < 4; s++){
    short8 B00 = fb[(0*8 + s*2 + 0)*64 + lane];
    short8 B01 = fb[(0*8 + s*2 + 1)*64 + lane];
    short8 B10 = fb[(1*8 + s*2 + 0)*64 + lane];
    short8 B11 = fb[(1*8 + s*2 + 1)*64 + lane];
    short8 B20 = fb[(2*8 + s*2 + 0)*64 + lane];
    short8 B21 = fb[(2*8 + s*2 + 1)*64 + lane];

    float c0[8], c1[8], c2[8];
    lerp_regs(R0[s],   R1[s],   w0, c0);
    lerp_regs(R0[4+s], R1[4+s], w1, c1);
    lerp_regs(R0[8+s], R1[8+s], w2, c2);

    uint4 A0u, A1u, A2u;
    A0u.x = pack2(c0[0]*c1[0], c0[1]*c1[1]);
    A0u.y = pack2(c0[2]*c1[2], c0[3]*c1[3]);
    A0u.z = pack2(c0[4]*c1[4], c0[5]*c1[5]);
    A0u.w = pack2(c0[6]*c1[6], c0[7]*c1[7]);
    A1u.x = pack2(c0[0]*c2[0], c0[1]*c2[1]);
    A1u.y = pack2(c0[2]*c2[2], c0[3]*c2[3]);
    A1u.z = pack2(c0[4]*c2[4], c0[5]*c2[5]);
    A1u.w = pack2(c0[6]*c2[6], c0[7]*c2[7]);
    A2u.x = pack2(c1[0]*c2[0], c1[1]*c2[1]);
    A2u.y = pack2(c1[2]*c2[2], c1[3]*c2[3]);
    A2u.z = pack2(c1[4]*c2[4], c1[5]*c2[5]);
    A2u.w = pack2(c1[6]*c2[6], c1[7]*c2[7]);
    short8 A0 = __builtin_bit_cast(short8, A0u);
    short8 A1 = __builtin_bit_cast(short8, A1u);
    short8 A2 = __builtin_bit_cast(short8, A2u);

    acc00 = __builtin_amdgcn_mfma_f32_16x16x32_bf16(A0, B00, acc00, 0, 0, 0);
    acc01 = __builtin_amdgcn_mfma_f32_16x16x32_bf16(A0, B01, acc01, 0, 0, 0);
    acc10 = __builtin_amdgcn_mfma_f32_16x16x32_bf16(A1, B10, acc10, 0, 0, 0);
    acc11 = __builtin_amdgcn_mfma_f32_16x16x32_bf16(A1, B11, acc11, 0, 0, 0);
    acc20 = __builtin_amdgcn_mfma_f32_16x16x32_bf16(A2, B20, acc20, 0, 0, 0);
    acc21 = __builtin_amdgcn_mfma_f32_16x16x32_bf16(A2, B21, acc21, 0, 0, 0);
  }

  const int rowBase = tile*16 + q*4;
  #pragma unroll
  for (int v = 0; v < 4; v++){
    float* o = out + (size_t)(rowBase + v)*102 + 6 + m;
    o[0]  = acc00[v];
    o[16] = acc01[v];
    o[32] = acc10[v];
    o[48] = acc11[v];
    o[64] = acc20[v];
    o[80] = acc21[v];
  }
}

extern "C" void kernel_launch(void* const* d_in, const int* in_sizes, int n_in,
                              void* d_out, int out_size, void* d_ws, size_t ws_size,
                              hipStream_t stream) {
  const float* pose_pts  = (const float*)d_in[0];
  const float* pose_dirs = (const float*)d_in[1];
  const float* sw        = (const float*)d_in[2];
  const float* Am        = (const float*)d_in[3];
  const float* Bm        = (const float*)d_in[4];
  const float* tb        = (const float*)d_in[5];
  const float* cl0       = (const float*)d_in[6];
  const float* cl1       = (const float*)d_in[7];
  const float* cl2       = (const float*)d_in[8];
  const float* fl0       = (const float*)d_in[9];
  const float* fl1       = (const float*)d_in[10];
  const float* fl2       = (const float*)d_in[11];
  const float* tw        = (const float*)d_in[12];
  const int*   tkid      = (const int*)d_in[13];
  float* out = (float*)d_out;

  hipLaunchKernelGGL(prep_skin, dim3(SKIN_BLOCKS + TRANS_BLOCKS + FEAT_BLOCKS), dim3(256), 0, stream,
                     pose_pts, pose_dirs, sw, Am, Bm, tb,
                     cl0, cl1, cl2, fl0, fl1, fl2, tw, tkid, out);
  hipLaunchKernelGGL(einsum_mfma, dim3(NPTS/(4*16)), dim3(256), 0, stream, out);
}

// Round 5
// 136.018 us; speedup vs baseline: 1.0150x; 1.0150x over previous
//
#include <hip/hip_runtime.h>

#define NPTS 131072
#define G0 512
#define G1 512
#define G2 128

#define SKIN_BLOCKS  512
#define TRANS_BLOCKS 144
#define FEAT_BLOCKS  48

#define OFF1 (4*G0*32)
#define OFF2 (4*(G0+G1)*32)
#define LTOT (4*(G0+G1+G2)*32)

typedef float v4f __attribute__((ext_vector_type(4)));
typedef __attribute__((ext_vector_type(8))) short short8;

// persistent device scratch (fully rewritten every launch)
__device__ unsigned short g_lines16[LTOT + 32];   // bf16 [axis][pose][g][r], 64-B rows, +pad
__device__ unsigned short g_featB[3*4*2*64*8];    // bf16 [plane][s][tcol][lane][j] MFMA-B order
__device__ float4 g_pos[NPTS];                    // raw grid positions per axis

__device__ __forceinline__ unsigned short bf16rne(float x){
  unsigned int u = __float_as_uint(x);
  u += 0x7fffu + ((u >> 16) & 1u);
  return (unsigned short)(u >> 16);
}

__device__ __forceinline__ void cvt8(uint4 r, float* f){
  f[0] = __uint_as_float(r.x << 16); f[1] = __uint_as_float(r.x & 0xffff0000u);
  f[2] = __uint_as_float(r.y << 16); f[3] = __uint_as_float(r.y & 0xffff0000u);
  f[4] = __uint_as_float(r.z << 16); f[5] = __uint_as_float(r.z & 0xffff0000u);
  f[6] = __uint_as_float(r.w << 16); f[7] = __uint_as_float(r.w & 0xffff0000u);
}

__device__ __forceinline__ void lerp_regs(uint4 r0, uint4 r1, float w, float* c){
  float a[8], b[8];
  cvt8(r0, a); cvt8(r1, b);
  #pragma unroll
  for (int j = 0; j < 8; j++) c[j] = fmaf(w, b[j] - a[j], a[j]);
}

// pack two fp32 -> bf16x2 (lo in low half) via +0x8000 round, one v_perm
__device__ __forceinline__ unsigned int pack2(float lo, float hi){
  unsigned int ul = __float_as_uint(lo) + 0x8000u;
  unsigned int uh = __float_as_uint(hi) + 0x8000u;
  return __builtin_amdgcn_perm(uh, ul, 0x07060302u);
}

// ---------------- kernel 1: skin + bf16 line transpose + featB prep ----------------
__global__ __launch_bounds__(256) void prep_skin(
    const float* __restrict__ pts, const float* __restrict__ dirs,
    const float* __restrict__ sw,  const float* __restrict__ Am,
    const float* __restrict__ Bm,  const float* __restrict__ tb,
    const float* __restrict__ c0,  const float* __restrict__ c1,
    const float* __restrict__ c2,  const float* __restrict__ f0,
    const float* __restrict__ f1,  const float* __restrict__ f2,
    const float* __restrict__ tw,  const int* __restrict__ topk_id,
    float* __restrict__ out)
{
  const int bid = blockIdx.x;
  const int tid = threadIdx.x;

  if (bid >= SKIN_BLOCKS) {
    int pb = bid - SKIN_BLOCKS;
    if (pb < TRANS_BLOCKS) {
      // transpose, 4 r-values per thread: reads g-coalesced, writes 8-B units
      int e = pb*256 + tid;
      const float* src; int logG, outoff;
      if (e < 16384)      { src = c0; logG = 9; outoff = 0; }
      else if (e < 32768) { e -= 16384; src = c1; logG = 9; outoff = OFF1; }
      else                { e -= 32768; src = c2; logG = 7; outoff = OFF2; }
      const int G = 1 << logG;
      int g  = e & (G-1);
      int t  = e >> logG;
      int r4 = t & 7;
      int kk = t >> 3;
      int id = topk_id[kk];
      const float* s0 = src + (id*32 + r4*4)*G + g;
      float v0 = s0[0];
      float v1 = s0[G];
      float v2 = s0[2*G];
      float v3 = s0[3*G];
      unsigned int lo = ((unsigned int)bf16rne(v0)) | (((unsigned int)bf16rne(v1)) << 16);
      unsigned int hi = ((unsigned int)bf16rne(v2)) | (((unsigned int)bf16rne(v3)) << 16);
      uint2 w; w.x = lo; w.y = hi;
      *reinterpret_cast<uint2*>(&g_lines16[outoff + (kk*G + g)*32 + r4*4]) = w;
    } else {
      int e = (pb - TRANS_BLOCKS)*256 + tid;
      if (e < 3*4*2*64*8) {
        int j    =  e        & 7;
        int lane = (e >> 3)  & 63;
        int tcol = (e >> 9)  & 1;
        int s    = (e >> 10) & 3;
        int p    =  e >> 12;
        int r = ((lane >> 4) << 3) + j;
        int cc = tcol*16 + (lane & 15);
        const float* f = (p == 0) ? f0 : ((p == 1) ? f1 : f2);
        float v = tw[s] * f[(topk_id[s]*32 + r)*32 + cc];
        g_featB[e] = bf16rne(v);
      }
    }
    return;
  }

  // -------- skin path --------
  if (bid == 0 && tid < 32) g_lines16[LTOT + tid] = 0;  // finite pad

  __shared__ float sA[384];
  __shared__ float sB[384];
  for (int i = tid; i < 384; i += 256){ sA[i] = Am[i]; sB[i] = Bm[i]; }
  __syncthreads();

  const int n = bid*256 + tid;
  float swv[24];
  {
    const float4* swp = reinterpret_cast<const float4*>(sw + n*24);
    #pragma unroll
    for (int i = 0; i < 6; i++){
      float4 v = swp[i];
      swv[4*i] = v.x; swv[4*i+1] = v.y; swv[4*i+2] = v.z; swv[4*i+3] = v.w;
    }
  }
  float RA[9] = {0,0,0,0,0,0,0,0,0}, tA[3] = {0,0,0};
  float RB[9] = {0,0,0,0,0,0,0,0,0}, tB[3] = {0,0,0};
  #pragma unroll
  for (int j = 0; j < 24; j++){
    float w = swv[j];
    const float* a = sA + j*16;
    const float* b = sB + j*16;
    RA[0] = fmaf(w, a[0], RA[0]); RA[1] = fmaf(w, a[1], RA[1]); RA[2] = fmaf(w, a[2], RA[2]); tA[0] = fmaf(w, a[3],  tA[0]);
    RA[3] = fmaf(w, a[4], RA[3]); RA[4] = fmaf(w, a[5], RA[4]); RA[5] = fmaf(w, a[6], RA[5]); tA[1] = fmaf(w, a[7],  tA[1]);
    RA[6] = fmaf(w, a[8], RA[6]); RA[7] = fmaf(w, a[9], RA[7]); RA[8] = fmaf(w, a[10],RA[8]); tA[2] = fmaf(w, a[11], tA[2]);
    RB[0] = fmaf(w, b[0], RB[0]); RB[1] = fmaf(w, b[1], RB[1]); RB[2] = fmaf(w, b[2], RB[2]); tB[0] = fmaf(w, b[3],  tB[0]);
    RB[3] = fmaf(w, b[4], RB[3]); RB[4] = fmaf(w, b[5], RB[4]); RB[5] = fmaf(w, b[6], RB[5]); tB[1] = fmaf(w, b[7],  tB[1]);
    RB[6] = fmaf(w, b[8], RB[6]); RB[7] = fmaf(w, b[9], RB[7]); RB[8] = fmaf(w, b[10],RB[8]); tB[2] = fmaf(w, b[11], tB[2]);
  }
  float c00 = RA[4]*RA[8] - RA[5]*RA[7];
  float c01 = RA[5]*RA[6] - RA[3]*RA[8];
  float c02 = RA[3]*RA[7] - RA[4]*RA[6];
  float det = RA[0]*c00 + RA[1]*c01 + RA[2]*c02;
  float idet = 1.0f/det;
  float i00 = c00*idet;
  float i01 = (RA[2]*RA[7] - RA[1]*RA[8])*idet;
  float i02 = (RA[1]*RA[5] - RA[2]*RA[4])*idet;
  float i10 = c01*idet;
  float i11 = (RA[0]*RA[8] - RA[2]*RA[6])*idet;
  float i12 = (RA[2]*RA[3] - RA[0]*RA[5])*idet;
  float i20 = c02*idet;
  float i21 = (RA[1]*RA[6] - RA[0]*RA[7])*idet;
  float i22 = (RA[0]*RA[4] - RA[1]*RA[3])*idet;

  float px = pts[n*3+0], py = pts[n*3+1], pz = pts[n*3+2];
  float dx = dirs[n*3+0], dy = dirs[n*3+1], dz = dirs[n*3+2];
  float qx = px - tA[0], qy = py - tA[1], qz = pz - tA[2];
  float tpx = i00*qx + i01*qy + i02*qz;
  float tpy = i10*qx + i11*qy + i12*qz;
  float tpz = i20*qx + i21*qy + i22*qz;
  float cx = RB[0]*tpx + RB[1]*tpy + RB[2]*tpz + tB[0];
  float cy = RB[3]*tpx + RB[4]*tpy + RB[5]*tpz + tB[1];
  float cz = RB[6]*tpx + RB[7]*tpy + RB[8]*tpz + tB[2];
  float tdx = i00*dx + i01*dy + i02*dz;
  float tdy = i10*dx + i11*dy + i12*dz;
  float tdz = i20*dx + i21*dy + i22*dz;
  float cdx = RB[0]*tdx + RB[1]*tdy + RB[2]*tdz;
  float cdy = RB[3]*tdx + RB[4]*tdy + RB[5]*tdz;
  float cdz = RB[6]*tdx + RB[7]*tdy + RB[8]*tdz;

  {
    // row base n*408 B is 8-B aligned -> three float2 stores
    float2* o2 = reinterpret_cast<float2*>(out + (size_t)n*102);
    float2 a; a.x = cx;  a.y = cy;
    float2 b; b.x = cz;  b.y = cdx;
    float2 c; c.x = cdy; c.y = cdz;
    o2[0] = a; o2[1] = b; o2[2] = c;
  }
  {
    float lo0 = tb[0], lo1 = tb[1], lo2 = tb[2];
    float hi0 = tb[3], hi1 = tb[4], hi2 = tb[5];
    float x0 = (cx - lo0)/(hi0 - lo0)*2.0f - 1.0f;
    float x1 = (cy - lo1)/(hi1 - lo1)*2.0f - 1.0f;
    float x2 = (cz - lo2)/(hi2 - lo2)*2.0f - 1.0f;
    float4 p;
    p.x = (x0 + 1.0f)*0.5f*(float)(G0-1);
    p.y = (x1 + 1.0f)*0.5f*(float)(G1-1);
    p.z = (x2 + 1.0f)*0.5f*(float)(G2-1);
    p.w = 0.0f;
    g_pos[n] = p;
  }
}

// ---------------- kernel 2: einsum via MFMA, 2 tiles (32 pts) per wave ----------------
__global__ __launch_bounds__(256) void einsum_mfma(float* __restrict__ out)
{
  const int tid  = threadIdx.x;
  const int lane = tid & 63;
  const int wv   = tid >> 6;
  const int m    = lane & 15;
  const int q    = lane >> 4;
  const int tileBase = (blockIdx.x*4 + wv)*2;   // 4096 waves x 2 tiles = 8192 tiles

  const unsigned short* lt0 = g_lines16;
  const unsigned short* lt1 = g_lines16 + OFF1;
  const unsigned short* lt2 = g_lines16 + OFF2;
  const short8* fb = reinterpret_cast<const short8*>(g_featB);

  int a0[2], a1[2], a2[2];
  float w0[2], w1[2], w2[2];
  #pragma unroll
  for (int i = 0; i < 2; i++){
    float4 pos = g_pos[(tileBase + i)*16 + m];
    float pc0 = fminf(fmaxf(pos.x, 0.0f), (float)(G0-1));
    float pc1 = fminf(fmaxf(pos.y, 0.0f), (float)(G1-1));
    float pc2 = fminf(fmaxf(pos.z, 0.0f), (float)(G2-1));
    float fl0 = floorf(pc0), fl1 = floorf(pc1), fl2 = floorf(pc2);
    a0[i] = (int)fl0; a1[i] = (int)fl1; a2[i] = (int)fl2;
    w0[i] = pc0 - fl0; w1[i] = pc1 - fl1; w2[i] = pc2 - fl2;
  }

  v4f acc[2][6];
  #pragma unroll
  for (int i = 0; i < 2; i++)
    #pragma unroll
    for (int p = 0; p < 6; p++) acc[i][p] = (v4f){0,0,0,0};

  #pragma unroll
  for (int s = 0; s < 4; s++){
    // B fragments: loaded ONCE per s, reused across both tiles
    short8 B00 = fb[(0*8 + s*2 + 0)*64 + lane];
    short8 B01 = fb[(0*8 + s*2 + 1)*64 + lane];
    short8 B10 = fb[(1*8 + s*2 + 0)*64 + lane];
    short8 B11 = fb[(1*8 + s*2 + 1)*64 + lane];
    short8 B20 = fb[(2*8 + s*2 + 0)*64 + lane];
    short8 B21 = fb[(2*8 + s*2 + 1)*64 + lane];

    // issue all 12 row-pair loads for both tiles up front (MLP)
    uint4 r0a[2], r1a[2], r0b[2], r1b[2], r0c[2], r1c[2];
    #pragma unroll
    for (int i = 0; i < 2; i++){
      const unsigned short* p0 = lt0 + (s*G0 + a0[i])*32 + q*8;
      r0a[i] = *(const uint4*)p0;  r1a[i] = *(const uint4*)(p0 + 32);
      const unsigned short* p1 = lt1 + (s*G1 + a1[i])*32 + q*8;
      r0b[i] = *(const uint4*)p1;  r1b[i] = *(const uint4*)(p1 + 32);
      const unsigned short* p2 = lt2 + (s*G2 + a2[i])*32 + q*8;
      r0c[i] = *(const uint4*)p2;  r1c[i] = *(const uint4*)(p2 + 32);
    }

    #pragma unroll
    for (int i = 0; i < 2; i++){
      float c0[8], c1[8], c2[8];
      lerp_regs(r0a[i], r1a[i], w0[i], c0);
      lerp_regs(r0b[i], r1b[i], w1[i], c1);
      lerp_regs(r0c[i], r1c[i], w2[i], c2);

      uint4 A0u, A1u, A2u;
      A0u.x = pack2(c0[0]*c1[0], c0[1]*c1[1]);
      A0u.y = pack2(c0[2]*c1[2], c0[3]*c1[3]);
      A0u.z = pack2(c0[4]*c1[4], c0[5]*c1[5]);
      A0u.w = pack2(c0[6]*c1[6], c0[7]*c1[7]);
      A1u.x = pack2(c0[0]*c2[0], c0[1]*c2[1]);
      A1u.y = pack2(c0[2]*c2[2], c0[3]*c2[3]);
      A1u.z = pack2(c0[4]*c2[4], c0[5]*c2[5]);
      A1u.w = pack2(c0[6]*c2[6], c0[7]*c2[7]);
      A2u.x = pack2(c1[0]*c2[0], c1[1]*c2[1]);
      A2u.y = pack2(c1[2]*c2[2], c1[3]*c2[3]);
      A2u.z = pack2(c1[4]*c2[4], c1[5]*c2[5]);
      A2u.w = pack2(c1[6]*c2[6], c1[7]*c2[7]);
      short8 A0 = __builtin_bit_cast(short8, A0u);
      short8 A1 = __builtin_bit_cast(short8, A1u);
      short8 A2 = __builtin_bit_cast(short8, A2u);

      acc[i][0] = __builtin_amdgcn_mfma_f32_16x16x32_bf16(A0, B00, acc[i][0], 0, 0, 0);
      acc[i][1] = __builtin_amdgcn_mfma_f32_16x16x32_bf16(A0, B01, acc[i][1], 0, 0, 0);
      acc[i][2] = __builtin_amdgcn_mfma_f32_16x16x32_bf16(A1, B10, acc[i][2], 0, 0, 0);
      acc[i][3] = __builtin_amdgcn_mfma_f32_16x16x32_bf16(A1, B11, acc[i][3], 0, 0, 0);
      acc[i][4] = __builtin_amdgcn_mfma_f32_16x16x32_bf16(A2, B20, acc[i][4], 0, 0, 0);
      acc[i][5] = __builtin_amdgcn_mfma_f32_16x16x32_bf16(A2, B21, acc[i][5], 0, 0, 0);
    }
  }

  #pragma unroll
  for (int i = 0; i < 2; i++){
    const int rowBase = (tileBase + i)*16 + q*4;
    #pragma unroll
    for (int v = 0; v < 4; v++){
      float* o = out + (size_t)(rowBase + v)*102 + 6 + m;
      o[0]  = acc[i][0][v];
      o[16] = acc[i][1][v];
      o[32] = acc[i][2][v];
      o[48] = acc[i][3][v];
      o[64] = acc[i][4][v];
      o[80] = acc[i][5][v];
    }
  }
}

extern "C" void kernel_launch(void* const* d_in, const int* in_sizes, int n_in,
                              void* d_out, int out_size, void* d_ws, size_t ws_size,
                              hipStream_t stream) {
  const float* pose_pts  = (const float*)d_in[0];
  const float* pose_dirs = (const float*)d_in[1];
  const float* sw        = (const float*)d_in[2];
  const float* Am        = (const float*)d_in[3];
  const float* Bm        = (const float*)d_in[4];
  const float* tb        = (const float*)d_in[5];
  const float* cl0       = (const float*)d_in[6];
  const float* cl1       = (const float*)d_in[7];
  const float* cl2       = (const float*)d_in[8];
  const float* fl0       = (const float*)d_in[9];
  const float* fl1       = (const float*)d_in[10];
  const float* fl2       = (const float*)d_in[11];
  const float* tw        = (const float*)d_in[12];
  const int*   tkid      = (const int*)d_in[13];
  float* out = (float*)d_out;

  hipLaunchKernelGGL(prep_skin, dim3(SKIN_BLOCKS + TRANS_BLOCKS + FEAT_BLOCKS), dim3(256), 0, stream,
                     pose_pts, pose_dirs, sw, Am, Bm, tb,
                     cl0, cl1, cl2, fl0, fl1, fl2, tw, tkid, out);
  hipLaunchKernelGGL(einsum_mfma, dim3(NPTS/(8*16)), dim3(256), 0, stream, out);
}